// Round 4
// baseline (1417.902 us; speedup 1.0000x reference)
//
#include <hip/hip_runtime.h>
#include <math.h>
#include <limits.h>

#define EPSB 1e-5f
#define R2C  0.09f

// ---- workspace offsets (floats). Total ~4.44M floats = ~17.8 MB ----
#define OFF_MASKF 0          // N*16
#define OFF_KERNF 1600000    // N*16  (dead after k_prep -> merge partials live here)
#define OFF_STATS 3200000    // (unused now, kept for layout stability)
#define OFF_VT    3202048    // 128*352
#define OFF_FEATW 3247104    // 128*36
#define OFF_MZ1   3251712    // 16384*36  (dead until k_merge1 -> tower partials live here)
#define OFF_MZ2   3841536    // 16384*36
#define OFF_INT   4431360    // 256 ints (topk 128 | cand_batch 128)

// ============================ fused tower layer ===========================
// blockIdx.y = tower (0: mask, 1: kernel).
// BN stats: producer blocks write per-block partial (sum,sumsq) rows
// NON-ATOMICALLY to tp_out[(tw*gridDim.x + blk)*64 + {0..63}]; consumer
// reduces at head with 4 independent fp64 accumulators (loads pipeline).
// Stats computed from the As stage-out tile via LDS column sums.
template <int COLS>
__global__ __launch_bounds__(256)
void k_tower2(const float* __restrict__ X0, const float* __restrict__ X1,
              const float* __restrict__ W0, const float* __restrict__ W1,
              const float* __restrict__ b0, const float* __restrict__ b1,
              float* __restrict__ Y0, float* __restrict__ Y1,
              const double* __restrict__ tp_in, double* __restrict__ tp_out,
              int N) {
    __shared__ float As[256 * 33];
    __shared__ float mrs[64];
    __shared__ float redS[256];
    __shared__ float redQ[256];
    __shared__ double redd[256];
    int tid = threadIdx.x;
    int tw = blockIdx.y;
    const float* X = tw ? X1 : X0;
    const float* W = tw ? W1 : W0;
    const float* bias = tw ? b1 : b0;
    float* Y = tw ? Y1 : Y0;

    bool nrm = (tp_in != nullptr);
    if (nrm) {
        // reduce gridDim.x per-block partials (cols 0..31 = sum, 32..63 = sumsq)
        int col = tid & 63, part = tid >> 6;
        const double* src = tp_in + (size_t)tw * gridDim.x * 64 + col;
        int nb = (int)gridDim.x;
        double a0 = 0.0, a1 = 0.0, a2 = 0.0, a3 = 0.0;
        int b = part;
        for (; b + 12 < nb; b += 16) {
            a0 += src[(size_t)b * 64];
            a1 += src[(size_t)(b + 4) * 64];
            a2 += src[(size_t)(b + 8) * 64];
            a3 += src[(size_t)(b + 12) * 64];
        }
        for (; b < nb; b += 4) a0 += src[(size_t)b * 64];
        redd[part * 64 + col] = (a0 + a1) + (a2 + a3);
        __syncthreads();
        if (tid < 32) {
            double S = redd[tid] + redd[64 + tid] + redd[128 + tid] + redd[192 + tid];
            double Q = redd[32 + tid] + redd[96 + tid] + redd[160 + tid] + redd[224 + tid];
            double m = S / (double)N;
            double v = Q / (double)N - m * m;
            mrs[tid] = (float)m; mrs[32 + tid] = (float)rsqrt(v + (double)EPSB);
        }
    }
    __syncthreads();
    int rbase = blockIdx.x * 256;
    int rmax = N - rbase; if (rmax > 256) rmax = 256;
    // ---- coalesced stage-in (+BN/ReLU) ----
    const float4* Xv = (const float4*)(X + (size_t)rbase * 32);
    for (int f = tid; f < 2048; f += 256) {
        int r = f >> 3, c0 = (f & 7) * 4;
        float4 v = make_float4(0.f, 0.f, 0.f, 0.f);
        if (r < rmax) v = Xv[f];
        float e[4] = {v.x, v.y, v.z, v.w};
        float* dst = &As[r * 33 + c0];
#pragma unroll
        for (int u = 0; u < 4; u++) {
            float t = e[u];
            if (nrm) t = fmaxf((t - mrs[c0 + u]) * mrs[32 + c0 + u], 0.f);
            dst[u] = t;
        }
    }
    __syncthreads();
    // ---- compute: one row per thread ----
    float acc[COLS];
#pragma unroll
    for (int j = 0; j < COLS; j++) acc[j] = 0.f;
    if (bias) {
#pragma unroll
        for (int j = 0; j < COLS; j++) acc[j] = bias[j];
    }
#pragma unroll 4
    for (int k = 0; k < 32; k++) {
        float a = As[tid * 33 + k];
        const float* wr = W + k * COLS;   // wave-uniform -> scalar loads
#pragma unroll
        for (int j = 0; j < COLS; j++) acc[j] = fmaf(a, wr[j], acc[j]);
    }
    // ---- stage acc into As (feeds both global write and stats) ----
    __syncthreads();
#pragma unroll
    for (int j = 0; j < COLS; j++) As[tid * 33 + j] = acc[j];
    __syncthreads();
    // ---- coalesced global write ----
    constexpr int C4 = COLS / 4;
    for (int f = tid; f < 256 * C4; f += 256) {
        int r = f / C4, c0 = (f % C4) * 4;
        if (r < rmax) {
            const float* sp = &As[r * 33 + c0];
            float4 o = {sp[0], sp[1], sp[2], sp[3]};
            *(float4*)(Y + (size_t)(rbase + r) * COLS + c0) = o;
        }
    }
    // ---- BN stats from As columns: per-block partials, NO atomics ----
    if constexpr (COLS == 32) {
        if (tp_out) {
            int j = tid & 31, g = tid >> 5;     // 8 groups x 32 rows each
            float s = 0.f, q = 0.f;
#pragma unroll
            for (int i = 0; i < 32; i++) {
                float v = As[(g * 32 + i) * 33 + j];   // bank (i+j)%32: conflict-free
                s += v; q = fmaf(v, v, q);
            }
            redS[tid] = s; redQ[tid] = q;
            __syncthreads();
            if (tid < 64) {
                int jj = tid & 31;
                const float* rp = (tid < 32) ? redS : redQ;
                double acc2 = 0.0;
#pragma unroll
                for (int g2 = 0; g2 < 8; g2++) acc2 += (double)rp[g2 * 32 + jj];
                tp_out[((size_t)tw * gridDim.x + blockIdx.x) * 64 + tid] = acc2;
            }
        }
    }
}

// ================================= NMS ====================================
#define NBINS 2048
#define NMC   1024
#define NCAP  1088
#define SLOTS 17
__global__ __launch_bounds__(1024)
void k_nms(const float* __restrict__ heat, const float* __restrict__ coords,
           const int* __restrict__ bidx, int N, int* __restrict__ topk) {
    __shared__ int   hist[NBINS];
    __shared__ float ch[NCAP], cxs[NCAP], cys[NCAP], czs[NCAP];
    __shared__ int   cid[NCAP];
    __shared__ int   sh_s, sh_e, sh_T, sh_cnt;
    __shared__ float sh_val;
    __shared__ float rv[16]; __shared__ int ri[16];
    __shared__ float fbx[32], fby[32], fbz[32];
    int b = blockIdx.x, tid = threadIdx.x;
    if (tid == 0) {
        int lo = 0, hi = N;
        while (lo < hi) { int m = (lo + hi) >> 1; if (bidx[m] < b) lo = m + 1; else hi = m; }
        sh_s = lo;
        lo = 0; hi = N;
        while (lo < hi) { int m = (lo + hi) >> 1; if (bidx[m] < b + 1) lo = m + 1; else hi = m; }
        sh_e = lo;
    }
    __syncthreads();
    int s = sh_s, e = sh_e, nb = e - s;
    if (nb <= 0) {
        if (tid < 32) topk[b * 32 + tid] = 0;
        return;
    }
    for (int i = tid; i < NBINS; i += 1024) hist[i] = 0;
    __syncthreads();
    for (int n = s + tid; n < e; n += 1024) {
        float h = heat[n];
        int bin = (int)(h * (float)NBINS);
        bin = min(max(bin, 0), NBINS - 1);
        atomicAdd(&hist[bin], 1);
    }
    __syncthreads();
    for (int off = 1; off < NBINS; off <<= 1) {
        int v[2];
#pragma unroll
        for (int u = 0; u < 2; u++) {
            int i = tid + u * 1024;
            v[u] = hist[i] + ((i + off < NBINS) ? hist[i + off] : 0);
        }
        __syncthreads();
#pragma unroll
        for (int u = 0; u < 2; u++) hist[tid + u * 1024] = v[u];
        __syncthreads();
    }
    int Meff = min(NMC, nb);
#pragma unroll
    for (int u = 0; u < 2; u++) {
        int i = tid + u * 1024;
        if (hist[i] >= Meff && (i == NBINS - 1 || hist[i + 1] < Meff)) sh_T = i;
    }
    if (tid == 0) sh_cnt = 0;
    __syncthreads();
    int T = sh_T;
    float thr = (float)T * (1.0f / (float)NBINS);
    for (int n = s + tid; n < e; n += 1024) {
        float h = heat[n];
        int bin = (int)(h * (float)NBINS);
        bin = min(max(bin, 0), NBINS - 1);
        if (bin >= T) {
            int p = atomicAdd(&sh_cnt, 1);
            if (p < NCAP) {
                ch[p] = h; cid[p] = n;
                cxs[p] = coords[(size_t)n * 3 + 0];
                cys[p] = coords[(size_t)n * 3 + 1];
                czs[p] = coords[(size_t)n * 3 + 2];
            }
        }
    }
    __syncthreads();
    int C = min(sh_cnt, NCAP);
    bool overflow = (sh_cnt > NCAP);
    if (tid < 64) {
        float hh[SLOTS], xx[SLOTS], yy[SLOTS], zz[SLOTS];
        int ii[SLOTS];
#pragma unroll
        for (int m = 0; m < SLOTS; m++) {
            int i = m * 64 + tid;
            if (i < C) { hh[m] = ch[i]; xx[m] = cxs[i]; yy[m] = cys[i]; zz[m] = czs[i]; ii[m] = cid[i]; }
            else { hh[m] = -INFINITY; xx[m] = 1e30f; yy[m] = 1e30f; zz[m] = 1e30f; ii[m] = INT_MAX; }
        }
        float last = -INFINITY;
        for (int t = 0; t < 32; t++) {
            float bv = -INFINITY, bx = 0.f, by = 0.f, bz = 0.f;
            int bo = INT_MAX;
#pragma unroll
            for (int m = 0; m < SLOTS; m++) {
                bool c = (hh[m] > bv) || (hh[m] == bv && ii[m] < bo);
                if (c) { bv = hh[m]; bo = ii[m]; bx = xx[m]; by = yy[m]; bz = zz[m]; }
            }
#pragma unroll
            for (int off = 32; off > 0; off >>= 1) {
                float ov = __shfl_down(bv, off);
                int   oo = __shfl_down(bo, off);
                float ox = __shfl_down(bx, off);
                float oy = __shfl_down(by, off);
                float oz = __shfl_down(bz, off);
                bool c = (ov > bv) || (ov == bv && oo < bo);
                if (c) { bv = ov; bo = oo; bx = ox; by = oy; bz = oz; }
            }
            bv = __shfl(bv, 0); bo = __shfl(bo, 0);
            bx = __shfl(bx, 0); by = __shfl(by, 0); bz = __shfl(bz, 0);
            if (tid == 0) topk[b * 32 + t] = bo;
            last = bv;
#pragma unroll
            for (int m = 0; m < SLOTS; m++) {
                float dx = xx[m] - bx, dy = yy[m] - by, dz = zz[m] - bz;
                if (dx * dx + dy * dy + dz * dz < R2C) hh[m] = -INFINITY;
            }
        }
        if (tid == 0) sh_val = last;
    }
    __syncthreads();
    bool sound = (!overflow) && (C > 0) && (sh_val >= thr);
    if (!sound) {
        for (int t = 0; t < 32; t++) {
            float bv = -INFINITY; int bo = INT_MAX;
            for (int n = s + tid; n < e; n += 1024) {
                float x = coords[(size_t)n * 3], y = coords[(size_t)n * 3 + 1], z = coords[(size_t)n * 3 + 2];
                bool sup = false;
                for (int u = 0; u < t; u++) {
                    float dx = x - fbx[u], dy = y - fby[u], dz = z - fbz[u];
                    if (dx * dx + dy * dy + dz * dz < R2C) { sup = true; break; }
                }
                if (!sup) {
                    float h = heat[n];
                    if (h > bv || (h == bv && n < bo)) { bv = h; bo = n; }
                }
            }
#pragma unroll
            for (int off = 32; off > 0; off >>= 1) {
                float ov = __shfl_down(bv, off); int oo = __shfl_down(bo, off);
                if (ov > bv || (ov == bv && oo < bo)) { bv = ov; bo = oo; }
            }
            if ((tid & 63) == 0) { int w = tid >> 6; rv[w] = bv; ri[w] = bo; }
            __syncthreads();
            if (tid == 0) {
                bv = rv[0]; bo = ri[0];
                for (int w = 1; w < 16; w++)
                    if (rv[w] > bv || (rv[w] == bv && ri[w] < bo)) { bv = rv[w]; bo = ri[w]; }
                if (bo == INT_MAX) bo = 0;
                topk[b * 32 + t] = bo;
                fbx[t] = coords[(size_t)bo * 3];
                fby[t] = coords[(size_t)bo * 3 + 1];
                fbz[t] = coords[(size_t)bo * 3 + 2];
            }
            __syncthreads();
        }
    }
}

// ============================ instance prep ===============================
__global__ __launch_bounds__(384)
void k_prep(const int* __restrict__ topk, const float* __restrict__ coords,
            const int* __restrict__ bidx, const float* __restrict__ maskf,
            const float* __restrict__ kernf, const float* __restrict__ Wwg,
            const float* __restrict__ bwg, float* __restrict__ Vt,
            float* __restrict__ featw, int* __restrict__ cand_batch) {
    __shared__ float ck[16], cm[16], ctr[3], wrow[337];
    int i = blockIdx.x, tid = threadIdx.x;
    int idx = topk[i];
    if (tid < 16) { ck[tid] = kernf[(size_t)idx * 16 + tid]; cm[tid] = maskf[(size_t)idx * 16 + tid]; }
    else if (tid < 19) ctr[tid - 16] = coords[(size_t)idx * 3 + (tid - 16)];
    else if (tid == 19) cand_batch[i] = bidx[idx];
    __syncthreads();
    for (int c = tid; c < 337; c += 384) {
        float acc = bwg[c];
#pragma unroll
        for (int m = 0; m < 16; m++) acc += ck[m] * Wwg[m * 337 + c];
        wrow[c] = acc;
    }
    __syncthreads();
    for (int t = tid; t < 352; t += 384) {
        float v;
        if (t < 320) {
            int k = t >> 4, j = t & 15;
            if (k < 19) v = wrow[k * 16 + j];
            else {
                v = wrow[304 + j];
#pragma unroll
                for (int p = 0; p < 3; p++) v -= ctr[p] * wrow[(16 + p) * 16 + j];
            }
        } else if (t < 336) v = wrow[320 + (t - 320)];
        else if (t == 336) v = wrow[336];
        else v = 0.f;
        Vt[(size_t)i * 352 + t] = v;
    }
    for (int t = tid; t < 36; t += 384)
        featw[i * 36 + t] = (t < 16) ? ck[t] : (t < 32) ? cm[t - 16] : (t < 35) ? ctr[t - 32] : 0.f;
}

// ============================== mask heads ================================
// 2 points per thread x 4-wide j-groups: each float4 s_load of V feeds 8
// independent fma chains. __launch_bounds__(256, 4) raises the VGPR cap to
// 128 (4 waves/SIMD): round-3's default heuristic capped at 32 VGPRs and
// spilled a0/a1 to scratch (1 ms). ~65 VGPRs needed -> zero spill now.
#define MASK_PER 8
__global__ __launch_bounds__(256, 4)
void k_mask(const float* __restrict__ maskf, const float* __restrict__ coords,
            const float* __restrict__ Vt, float* __restrict__ out,
            int N, int ostride) {
    int tid = threadIdx.x;
    int n0 = blockIdx.x * 512 + tid;
    int n1 = n0 + 256;
    bool v0 = (n0 < N), v1 = (n1 < N);
    int c0 = v0 ? n0 : (N - 1);
    int c1 = v1 ? n1 : (N - 1);
    float a0[20], a1[20];
    {
        const float4* f0 = (const float4*)(maskf + (size_t)c0 * 16);
        float4 A = f0[0], B = f0[1], C = f0[2], D = f0[3];
        a0[0]=A.x; a0[1]=A.y; a0[2]=A.z; a0[3]=A.w;
        a0[4]=B.x; a0[5]=B.y; a0[6]=B.z; a0[7]=B.w;
        a0[8]=C.x; a0[9]=C.y; a0[10]=C.z; a0[11]=C.w;
        a0[12]=D.x; a0[13]=D.y; a0[14]=D.z; a0[15]=D.w;
        a0[16]=coords[(size_t)c0*3]; a0[17]=coords[(size_t)c0*3+1]; a0[18]=coords[(size_t)c0*3+2];
        const float4* f1 = (const float4*)(maskf + (size_t)c1 * 16);
        float4 E = f1[0], F = f1[1], G = f1[2], H = f1[3];
        a1[0]=E.x; a1[1]=E.y; a1[2]=E.z; a1[3]=E.w;
        a1[4]=F.x; a1[5]=F.y; a1[6]=F.z; a1[7]=F.w;
        a1[8]=G.x; a1[9]=G.y; a1[10]=G.z; a1[11]=G.w;
        a1[12]=H.x; a1[13]=H.y; a1[14]=H.z; a1[15]=H.w;
        a1[16]=coords[(size_t)c1*3]; a1[17]=coords[(size_t)c1*3+1]; a1[18]=coords[(size_t)c1*3+2];
    }
    a0[19] = 1.f; a1[19] = 1.f;
    int ibase = blockIdx.y * MASK_PER;
    const float4* __restrict__ V4 = (const float4*)(Vt + (size_t)ibase * 352);  // block-uniform
    float* o0 = out + (size_t)ibase * ostride + n0;
    for (int ii = 0; ii < MASK_PER; ii++) {
        float4 bb = V4[84];                 // V[336] = b2
        float acc0 = bb.x, acc1 = bb.x;
#pragma unroll
        for (int jg = 0; jg < 4; jg++) {
            float h00=0.f,h01=0.f,h02=0.f,h03=0.f;
            float h10=0.f,h11=0.f,h12=0.f,h13=0.f;
#pragma unroll
            for (int k = 0; k < 20; k++) {
                float4 w = V4[k * 4 + jg];  // V[k*16 + jg*4 .. +3], s_load_dwordx4
                float x0 = a0[k], x1 = a1[k];
                h00 = fmaf(x0, w.x, h00); h01 = fmaf(x0, w.y, h01);
                h02 = fmaf(x0, w.z, h02); h03 = fmaf(x0, w.w, h03);
                h10 = fmaf(x1, w.x, h10); h11 = fmaf(x1, w.y, h11);
                h12 = fmaf(x1, w.z, h12); h13 = fmaf(x1, w.w, h13);
            }
            float4 w2 = V4[80 + jg];        // V[320 + jg*4 .. +3]
            acc0 = fmaf(fmaxf(h00, 0.f), w2.x, acc0);
            acc0 = fmaf(fmaxf(h01, 0.f), w2.y, acc0);
            acc0 = fmaf(fmaxf(h02, 0.f), w2.z, acc0);
            acc0 = fmaf(fmaxf(h03, 0.f), w2.w, acc0);
            acc1 = fmaf(fmaxf(h10, 0.f), w2.x, acc1);
            acc1 = fmaf(fmaxf(h11, 0.f), w2.y, acc1);
            acc1 = fmaf(fmaxf(h12, 0.f), w2.z, acc1);
            acc1 = fmaf(fmaxf(h13, 0.f), w2.w, acc1);
        }
        if (v0) o0[0]   = 1.f / (1.f + __expf(-acc0));
        if (v1) o0[256] = 1.f / (1.f + __expf(-acc1));
        V4 += 88;                            // 352/4
        o0 += ostride;
    }
}

// ============================== merge tower ===============================
// BN stats: NO global atomics. Each block writes its partial (sum,sumsq)
// row [70 doubles] to pout[blk*70 + j]; consumer reduces 64 rows at head
// with 4 independent accumulators (fully unrolled -> loads pipeline).
__global__ __launch_bounds__(256)
void k_merge1(const float* __restrict__ featw, const float* __restrict__ Wg,
              float* __restrict__ Z, double* __restrict__ pout) {
    __shared__ float F[128 * 36];
    __shared__ double redm[280];
    int tid = threadIdx.x;
    for (int t = tid; t < 128 * 36; t += 256) F[t] = featw[t];
    __syncthreads();
    int id = blockIdx.x * 256 + tid;
    int a = id >> 7, b = id & 127;
    float d[35];
#pragma unroll
    for (int k = 0; k < 35; k++) d[k] = fmaxf(fabsf(F[a * 36 + k] - F[b * 36 + k]), 1e-6f);
    float z[35];
#pragma unroll
    for (int j = 0; j < 35; j++) z[j] = 0.f;
    for (int k = 0; k < 35; k++) {
        float dk = d[k];
        const float* wr = Wg + k * 35;
#pragma unroll
        for (int j = 0; j < 35; j++) z[j] += dk * wr[j];
    }
    int wv = tid >> 6;
#pragma unroll
    for (int j = 0; j < 35; j++) {
        float s = z[j], q = z[j] * z[j];
#pragma unroll
        for (int off = 32; off > 0; off >>= 1) { s += __shfl_down(s, off); q += __shfl_down(q, off); }
        if ((tid & 63) == 0) { redm[wv * 70 + j] = (double)s; redm[wv * 70 + 35 + j] = (double)q; }
    }
    __syncthreads();
    if (tid < 70) {
        double t = redm[tid] + redm[70 + tid] + redm[140 + tid] + redm[210 + tid];
        pout[(size_t)blockIdx.x * 70 + tid] = t;
    }
    float* zr = Z + (size_t)id * 36;
#pragma unroll
    for (int j = 0; j < 35; j++) zr[j] = z[j];
}

__global__ __launch_bounds__(256)
void k_merge_mid(const float* __restrict__ Zin, const float* __restrict__ Wg,
                 float* __restrict__ Zout, const double* __restrict__ pin,
                 double* __restrict__ pout) {
    __shared__ float nrm[70];
    __shared__ double sred[70];
    __shared__ double redm[280];
    int tid = threadIdx.x;
    if (tid < 70) {
        double a0 = 0.0, a1 = 0.0, a2 = 0.0, a3 = 0.0;
#pragma unroll
        for (int b = 0; b < 64; b += 4) {
            a0 += pin[(size_t)b * 70 + tid];
            a1 += pin[(size_t)(b + 1) * 70 + tid];
            a2 += pin[(size_t)(b + 2) * 70 + tid];
            a3 += pin[(size_t)(b + 3) * 70 + tid];
        }
        sred[tid] = (a0 + a1) + (a2 + a3);
    }
    __syncthreads();
    if (tid < 35) {
        double m = sred[tid] * (1.0 / 16384.0);
        double v = sred[35 + tid] * (1.0 / 16384.0) - m * m;
        nrm[tid] = (float)m; nrm[35 + tid] = (float)rsqrt(v + (double)EPSB);
    }
    __syncthreads();
    int id = blockIdx.x * 256 + tid;
    const float* zi = Zin + (size_t)id * 36;
    float x[35];
#pragma unroll
    for (int k = 0; k < 35; k++) x[k] = fmaxf((zi[k] - nrm[k]) * nrm[35 + k], 0.f);
    float z[35];
#pragma unroll
    for (int j = 0; j < 35; j++) z[j] = 0.f;
    for (int k = 0; k < 35; k++) {
        float dk = x[k];
        const float* wr = Wg + k * 35;
#pragma unroll
        for (int j = 0; j < 35; j++) z[j] += dk * wr[j];
    }
    int wv = tid >> 6;
#pragma unroll
    for (int j = 0; j < 35; j++) {
        float s = z[j], q = z[j] * z[j];
#pragma unroll
        for (int off = 32; off > 0; off >>= 1) { s += __shfl_down(s, off); q += __shfl_down(q, off); }
        if ((tid & 63) == 0) { redm[wv * 70 + j] = (double)s; redm[wv * 70 + 35 + j] = (double)q; }
    }
    __syncthreads();
    if (tid < 70) {
        double t = redm[tid] + redm[70 + tid] + redm[140 + tid] + redm[210 + tid];
        pout[(size_t)blockIdx.x * 70 + tid] = t;
    }
    float* zr = Zout + (size_t)id * 36;
#pragma unroll
    for (int j = 0; j < 35; j++) zr[j] = z[j];
}

__global__ __launch_bounds__(256)
void k_merge_out(const float* __restrict__ Zin, const float* __restrict__ Wout,
                 const float* __restrict__ bout, const double* __restrict__ pin,
                 const int* __restrict__ cand_batch, float* __restrict__ out,
                 int N, int ostride) {
    __shared__ float nrm[70];
    __shared__ double sred[70];
    __shared__ int cb[128];
    int tid = threadIdx.x;
    if (tid < 70) {
        double a0 = 0.0, a1 = 0.0, a2 = 0.0, a3 = 0.0;
#pragma unroll
        for (int b = 0; b < 64; b += 4) {
            a0 += pin[(size_t)b * 70 + tid];
            a1 += pin[(size_t)(b + 1) * 70 + tid];
            a2 += pin[(size_t)(b + 2) * 70 + tid];
            a3 += pin[(size_t)(b + 3) * 70 + tid];
        }
        sred[tid] = (a0 + a1) + (a2 + a3);
    }
    if (tid >= 128 && tid < 256) cb[tid - 128] = cand_batch[tid - 128];
    __syncthreads();
    if (tid < 35) {
        double m = sred[tid] * (1.0 / 16384.0);
        double v = sred[35 + tid] * (1.0 / 16384.0) - m * m;
        nrm[tid] = (float)m; nrm[35 + tid] = (float)rsqrt(v + (double)EPSB);
    }
    __syncthreads();
    int id = blockIdx.x * 256 + tid;
    int a = id >> 7, b = id & 127;
    const float* zi = Zin + (size_t)id * 36;
    float s = bout[0];
    for (int k = 0; k < 35; k++)
        s += fmaxf((zi[k] - nrm[k]) * nrm[35 + k], 0.f) * Wout[k];
    float v = 1.f / (1.f + __expf(-s));
    if (cb[a] != cb[b]) v = 0.f;
    out[(size_t)a * ostride + N + b] = v;
}

// =============================== launcher =================================
extern "C" void kernel_launch(void* const* d_in, const int* in_sizes, int n_in,
                              void* d_out, int out_size, void* d_ws, size_t ws_size,
                              hipStream_t stream) {
    const float* of     = (const float*)d_in[0];
    const float* coords = (const float*)d_in[1];
    const float* heat   = (const float*)d_in[2];
    const int*   bidx   = (const int*)d_in[3];
    const float* Wm     = (const float*)d_in[4];
    const float* Wm_out = (const float*)d_in[5];
    const float* bm_out = (const float*)d_in[6];
    const float* Wk     = (const float*)d_in[7];
    const float* Wk_out = (const float*)d_in[8];
    const float* bk_out = (const float*)d_in[9];
    const float* Wg     = (const float*)d_in[10];
    const float* Wg_out = (const float*)d_in[11];
    const float* bg_out = (const float*)d_in[12];
    const float* Wwg    = (const float*)d_in[13];
    const float* bwg    = (const float*)d_in[14];
    float* out = (float*)d_out;
    float* ws  = (float*)d_ws;

    int N = in_sizes[0] / 32;          // 100000
    int ostride = N + 128;             // 100128

    float*  maskf = ws + OFF_MASKF;
    float*  kernf = ws + OFF_KERNF;
    float*  Vt    = ws + OFF_VT;
    float*  featw = ws + OFF_FEATW;
    float*  mz1   = ws + OFF_MZ1;
    float*  mz2   = ws + OFF_MZ2;
    int*    topk  = (int*)(ws + OFF_INT);
    int*    cand_batch = topk + 128;

    // tower BN partials ping-pong in mz1 region (dead until k_merge1):
    double* TPA = (double*)(ws + OFF_MZ1);
    double* TPB = (double*)(ws + OFF_MZ1 + 131072);
    // merge BN partials in kernf region (dead after k_prep):
    double* P1 = (double*)(ws + OFF_KERNF);
    double* P2 = (double*)(ws + OFF_KERNF + 16384);
    double* P3 = (double*)(ws + OFF_KERNF + 32768);

    // tower ping-pong buffers live inside d_out (overwritten before epilogue)
    float* bufAm = out;
    float* bufBm = out + (size_t)N * 32;
    float* bufAk = out + (size_t)N * 64;
    float* bufBk = out + (size_t)N * 96;

    dim3 tg2((N + 255) / 256, 2);

    k_nms<<<4, 1024, 0, stream>>>(heat, coords, bidx, N, topk);
    // both towers per launch (blockIdx.y selects); stats partials ping-pong TPA/TPB
    k_tower2<32><<<tg2, 256, 0, stream>>>(of,    of,    Wm,        Wk,        nullptr, nullptr, bufAm, bufAk, nullptr, TPA,     N);
    k_tower2<32><<<tg2, 256, 0, stream>>>(bufAm, bufAk, Wm + 1024, Wk + 1024, nullptr, nullptr, bufBm, bufBk, TPA,     TPB,     N);
    k_tower2<32><<<tg2, 256, 0, stream>>>(bufBm, bufBk, Wm + 2048, Wk + 2048, nullptr, nullptr, bufAm, bufAk, TPB,     TPA,     N);
    k_tower2<16><<<tg2, 256, 0, stream>>>(bufAm, bufAk, Wm_out,    Wk_out,    bm_out,  bk_out,  maskf, kernf, TPA,     nullptr, N);

    k_prep<<<128, 384, 0, stream>>>(topk, coords, bidx, maskf, kernf, Wwg, bwg,
                                    Vt, featw, cand_batch);
    k_mask<<<dim3((N + 511) / 512, 16), 256, 0, stream>>>(maskf, coords, Vt, out, N, ostride);

    k_merge1<<<64, 256, 0, stream>>>(featw, Wg, mz1, P1);
    k_merge_mid<<<64, 256, 0, stream>>>(mz1, Wg + 1225, mz2, P1, P2);
    k_merge_mid<<<64, 256, 0, stream>>>(mz2, Wg + 2450, mz1, P2, P3);
    k_merge_out<<<64, 256, 0, stream>>>(mz1, Wg_out, bg_out, P3, cand_batch,
                                        out, N, ostride);
}

// Round 5
// 568.111 us; speedup vs baseline: 2.4958x; 2.4958x over previous
//
#include <hip/hip_runtime.h>
#include <math.h>
#include <limits.h>

#define EPSB 1e-5f
#define R2C  0.09f

// ---- workspace offsets (floats). Total ~4.44M floats = ~17.8 MB ----
#define OFF_MASKF 0          // N*16
#define OFF_KERNF 1600000    // N*16  (dead after k_prep -> merge partials live here)
#define OFF_STATS 3200000    // (unused now, kept for layout stability)
#define OFF_VT    3202048    // 128*352
#define OFF_FEATW 3247104    // 128*36
#define OFF_MZ1   3251712    // 16384*36  (dead until k_merge1 -> tower partials live here)
#define OFF_MZ2   3841536    // 16384*36
#define OFF_INT   4431360    // 256 ints (topk 128 | cand_batch 128)

// ============================ fused tower layer ===========================
// blockIdx.y = tower (0: mask, 1: kernel).
// BN stats: producer blocks write per-block partial (sum,sumsq) rows
// NON-ATOMICALLY to tp_out[(tw*gridDim.x + blk)*64 + {0..63}]; consumer
// reduces at head with 4 independent fp64 accumulators (loads pipeline).
// Stats computed from the As stage-out tile via LDS column sums.
template <int COLS>
__global__ __launch_bounds__(256)
void k_tower2(const float* __restrict__ X0, const float* __restrict__ X1,
              const float* __restrict__ W0, const float* __restrict__ W1,
              const float* __restrict__ b0, const float* __restrict__ b1,
              float* __restrict__ Y0, float* __restrict__ Y1,
              const double* __restrict__ tp_in, double* __restrict__ tp_out,
              int N) {
    __shared__ float As[256 * 33];
    __shared__ float mrs[64];
    __shared__ float redS[256];
    __shared__ float redQ[256];
    __shared__ double redd[256];
    int tid = threadIdx.x;
    int tw = blockIdx.y;
    const float* X = tw ? X1 : X0;
    const float* W = tw ? W1 : W0;
    const float* bias = tw ? b1 : b0;
    float* Y = tw ? Y1 : Y0;

    bool nrm = (tp_in != nullptr);
    if (nrm) {
        // reduce gridDim.x per-block partials (cols 0..31 = sum, 32..63 = sumsq)
        int col = tid & 63, part = tid >> 6;
        const double* src = tp_in + (size_t)tw * gridDim.x * 64 + col;
        int nb = (int)gridDim.x;
        double a0 = 0.0, a1 = 0.0, a2 = 0.0, a3 = 0.0;
        int b = part;
        for (; b + 12 < nb; b += 16) {
            a0 += src[(size_t)b * 64];
            a1 += src[(size_t)(b + 4) * 64];
            a2 += src[(size_t)(b + 8) * 64];
            a3 += src[(size_t)(b + 12) * 64];
        }
        for (; b < nb; b += 4) a0 += src[(size_t)b * 64];
        redd[part * 64 + col] = (a0 + a1) + (a2 + a3);
        __syncthreads();
        if (tid < 32) {
            double S = redd[tid] + redd[64 + tid] + redd[128 + tid] + redd[192 + tid];
            double Q = redd[32 + tid] + redd[96 + tid] + redd[160 + tid] + redd[224 + tid];
            double m = S / (double)N;
            double v = Q / (double)N - m * m;
            mrs[tid] = (float)m; mrs[32 + tid] = (float)rsqrt(v + (double)EPSB);
        }
    }
    __syncthreads();
    int rbase = blockIdx.x * 256;
    int rmax = N - rbase; if (rmax > 256) rmax = 256;
    // ---- coalesced stage-in (+BN/ReLU) ----
    const float4* Xv = (const float4*)(X + (size_t)rbase * 32);
    for (int f = tid; f < 2048; f += 256) {
        int r = f >> 3, c0 = (f & 7) * 4;
        float4 v = make_float4(0.f, 0.f, 0.f, 0.f);
        if (r < rmax) v = Xv[f];
        float e[4] = {v.x, v.y, v.z, v.w};
        float* dst = &As[r * 33 + c0];
#pragma unroll
        for (int u = 0; u < 4; u++) {
            float t = e[u];
            if (nrm) t = fmaxf((t - mrs[c0 + u]) * mrs[32 + c0 + u], 0.f);
            dst[u] = t;
        }
    }
    __syncthreads();
    // ---- compute: one row per thread ----
    float acc[COLS];
#pragma unroll
    for (int j = 0; j < COLS; j++) acc[j] = 0.f;
    if (bias) {
#pragma unroll
        for (int j = 0; j < COLS; j++) acc[j] = bias[j];
    }
#pragma unroll 4
    for (int k = 0; k < 32; k++) {
        float a = As[tid * 33 + k];
        const float* wr = W + k * COLS;   // wave-uniform -> scalar loads
#pragma unroll
        for (int j = 0; j < COLS; j++) acc[j] = fmaf(a, wr[j], acc[j]);
    }
    // ---- stage acc into As (feeds both global write and stats) ----
    __syncthreads();
#pragma unroll
    for (int j = 0; j < COLS; j++) As[tid * 33 + j] = acc[j];
    __syncthreads();
    // ---- coalesced global write ----
    constexpr int C4 = COLS / 4;
    for (int f = tid; f < 256 * C4; f += 256) {
        int r = f / C4, c0 = (f % C4) * 4;
        if (r < rmax) {
            const float* sp = &As[r * 33 + c0];
            float4 o = {sp[0], sp[1], sp[2], sp[3]};
            *(float4*)(Y + (size_t)(rbase + r) * COLS + c0) = o;
        }
    }
    // ---- BN stats from As columns: per-block partials, NO atomics ----
    if constexpr (COLS == 32) {
        if (tp_out) {
            int j = tid & 31, g = tid >> 5;     // 8 groups x 32 rows each
            float s = 0.f, q = 0.f;
#pragma unroll
            for (int i = 0; i < 32; i++) {
                float v = As[(g * 32 + i) * 33 + j];   // bank (i+j)%32: conflict-free
                s += v; q = fmaf(v, v, q);
            }
            redS[tid] = s; redQ[tid] = q;
            __syncthreads();
            if (tid < 64) {
                int jj = tid & 31;
                const float* rp = (tid < 32) ? redS : redQ;
                double acc2 = 0.0;
#pragma unroll
                for (int g2 = 0; g2 < 8; g2++) acc2 += (double)rp[g2 * 32 + jj];
                tp_out[((size_t)tw * gridDim.x + blockIdx.x) * 64 + tid] = acc2;
            }
        }
    }
}

// ================================= NMS ====================================
#define NBINS 2048
#define NMC   1024
#define NCAP  1088
#define SLOTS 17
__global__ __launch_bounds__(1024)
void k_nms(const float* __restrict__ heat, const float* __restrict__ coords,
           const int* __restrict__ bidx, int N, int* __restrict__ topk) {
    __shared__ int   hist[NBINS];
    __shared__ float ch[NCAP], cxs[NCAP], cys[NCAP], czs[NCAP];
    __shared__ int   cid[NCAP];
    __shared__ int   sh_s, sh_e, sh_T, sh_cnt;
    __shared__ float sh_val;
    __shared__ float rv[16]; __shared__ int ri[16];
    __shared__ float fbx[32], fby[32], fbz[32];
    int b = blockIdx.x, tid = threadIdx.x;
    if (tid == 0) {
        int lo = 0, hi = N;
        while (lo < hi) { int m = (lo + hi) >> 1; if (bidx[m] < b) lo = m + 1; else hi = m; }
        sh_s = lo;
        lo = 0; hi = N;
        while (lo < hi) { int m = (lo + hi) >> 1; if (bidx[m] < b + 1) lo = m + 1; else hi = m; }
        sh_e = lo;
    }
    __syncthreads();
    int s = sh_s, e = sh_e, nb = e - s;
    if (nb <= 0) {
        if (tid < 32) topk[b * 32 + tid] = 0;
        return;
    }
    for (int i = tid; i < NBINS; i += 1024) hist[i] = 0;
    __syncthreads();
    for (int n = s + tid; n < e; n += 1024) {
        float h = heat[n];
        int bin = (int)(h * (float)NBINS);
        bin = min(max(bin, 0), NBINS - 1);
        atomicAdd(&hist[bin], 1);
    }
    __syncthreads();
    for (int off = 1; off < NBINS; off <<= 1) {
        int v[2];
#pragma unroll
        for (int u = 0; u < 2; u++) {
            int i = tid + u * 1024;
            v[u] = hist[i] + ((i + off < NBINS) ? hist[i + off] : 0);
        }
        __syncthreads();
#pragma unroll
        for (int u = 0; u < 2; u++) hist[tid + u * 1024] = v[u];
        __syncthreads();
    }
    int Meff = min(NMC, nb);
#pragma unroll
    for (int u = 0; u < 2; u++) {
        int i = tid + u * 1024;
        if (hist[i] >= Meff && (i == NBINS - 1 || hist[i + 1] < Meff)) sh_T = i;
    }
    if (tid == 0) sh_cnt = 0;
    __syncthreads();
    int T = sh_T;
    float thr = (float)T * (1.0f / (float)NBINS);
    for (int n = s + tid; n < e; n += 1024) {
        float h = heat[n];
        int bin = (int)(h * (float)NBINS);
        bin = min(max(bin, 0), NBINS - 1);
        if (bin >= T) {
            int p = atomicAdd(&sh_cnt, 1);
            if (p < NCAP) {
                ch[p] = h; cid[p] = n;
                cxs[p] = coords[(size_t)n * 3 + 0];
                cys[p] = coords[(size_t)n * 3 + 1];
                czs[p] = coords[(size_t)n * 3 + 2];
            }
        }
    }
    __syncthreads();
    int C = min(sh_cnt, NCAP);
    bool overflow = (sh_cnt > NCAP);
    if (tid < 64) {
        float hh[SLOTS], xx[SLOTS], yy[SLOTS], zz[SLOTS];
        int ii[SLOTS];
#pragma unroll
        for (int m = 0; m < SLOTS; m++) {
            int i = m * 64 + tid;
            if (i < C) { hh[m] = ch[i]; xx[m] = cxs[i]; yy[m] = cys[i]; zz[m] = czs[i]; ii[m] = cid[i]; }
            else { hh[m] = -INFINITY; xx[m] = 1e30f; yy[m] = 1e30f; zz[m] = 1e30f; ii[m] = INT_MAX; }
        }
        float last = -INFINITY;
        for (int t = 0; t < 32; t++) {
            float bv = -INFINITY, bx = 0.f, by = 0.f, bz = 0.f;
            int bo = INT_MAX;
#pragma unroll
            for (int m = 0; m < SLOTS; m++) {
                bool c = (hh[m] > bv) || (hh[m] == bv && ii[m] < bo);
                if (c) { bv = hh[m]; bo = ii[m]; bx = xx[m]; by = yy[m]; bz = zz[m]; }
            }
#pragma unroll
            for (int off = 32; off > 0; off >>= 1) {
                float ov = __shfl_down(bv, off);
                int   oo = __shfl_down(bo, off);
                float ox = __shfl_down(bx, off);
                float oy = __shfl_down(by, off);
                float oz = __shfl_down(bz, off);
                bool c = (ov > bv) || (ov == bv && oo < bo);
                if (c) { bv = ov; bo = oo; bx = ox; by = oy; bz = oz; }
            }
            bv = __shfl(bv, 0); bo = __shfl(bo, 0);
            bx = __shfl(bx, 0); by = __shfl(by, 0); bz = __shfl(bz, 0);
            if (tid == 0) topk[b * 32 + t] = bo;
            last = bv;
#pragma unroll
            for (int m = 0; m < SLOTS; m++) {
                float dx = xx[m] - bx, dy = yy[m] - by, dz = zz[m] - bz;
                if (dx * dx + dy * dy + dz * dz < R2C) hh[m] = -INFINITY;
            }
        }
        if (tid == 0) sh_val = last;
    }
    __syncthreads();
    bool sound = (!overflow) && (C > 0) && (sh_val >= thr);
    if (!sound) {
        for (int t = 0; t < 32; t++) {
            float bv = -INFINITY; int bo = INT_MAX;
            for (int n = s + tid; n < e; n += 1024) {
                float x = coords[(size_t)n * 3], y = coords[(size_t)n * 3 + 1], z = coords[(size_t)n * 3 + 2];
                bool sup = false;
                for (int u = 0; u < t; u++) {
                    float dx = x - fbx[u], dy = y - fby[u], dz = z - fbz[u];
                    if (dx * dx + dy * dy + dz * dz < R2C) { sup = true; break; }
                }
                if (!sup) {
                    float h = heat[n];
                    if (h > bv || (h == bv && n < bo)) { bv = h; bo = n; }
                }
            }
#pragma unroll
            for (int off = 32; off > 0; off >>= 1) {
                float ov = __shfl_down(bv, off); int oo = __shfl_down(bo, off);
                if (ov > bv || (ov == bv && oo < bo)) { bv = ov; bo = oo; }
            }
            if ((tid & 63) == 0) { int w = tid >> 6; rv[w] = bv; ri[w] = bo; }
            __syncthreads();
            if (tid == 0) {
                bv = rv[0]; bo = ri[0];
                for (int w = 1; w < 16; w++)
                    if (rv[w] > bv || (rv[w] == bv && ri[w] < bo)) { bv = rv[w]; bo = ri[w]; }
                if (bo == INT_MAX) bo = 0;
                topk[b * 32 + t] = bo;
                fbx[t] = coords[(size_t)bo * 3];
                fby[t] = coords[(size_t)bo * 3 + 1];
                fbz[t] = coords[(size_t)bo * 3 + 2];
            }
            __syncthreads();
        }
    }
}

// ============================ instance prep ===============================
__global__ __launch_bounds__(384)
void k_prep(const int* __restrict__ topk, const float* __restrict__ coords,
            const int* __restrict__ bidx, const float* __restrict__ maskf,
            const float* __restrict__ kernf, const float* __restrict__ Wwg,
            const float* __restrict__ bwg, float* __restrict__ Vt,
            float* __restrict__ featw, int* __restrict__ cand_batch) {
    __shared__ float ck[16], cm[16], ctr[3], wrow[337];
    int i = blockIdx.x, tid = threadIdx.x;
    int idx = topk[i];
    if (tid < 16) { ck[tid] = kernf[(size_t)idx * 16 + tid]; cm[tid] = maskf[(size_t)idx * 16 + tid]; }
    else if (tid < 19) ctr[tid - 16] = coords[(size_t)idx * 3 + (tid - 16)];
    else if (tid == 19) cand_batch[i] = bidx[idx];
    __syncthreads();
    for (int c = tid; c < 337; c += 384) {
        float acc = bwg[c];
#pragma unroll
        for (int m = 0; m < 16; m++) acc += ck[m] * Wwg[m * 337 + c];
        wrow[c] = acc;
    }
    __syncthreads();
    for (int t = tid; t < 352; t += 384) {
        float v;
        if (t < 320) {
            int k = t >> 4, j = t & 15;
            if (k < 19) v = wrow[k * 16 + j];
            else {
                v = wrow[304 + j];
#pragma unroll
                for (int p = 0; p < 3; p++) v -= ctr[p] * wrow[(16 + p) * 16 + j];
            }
        } else if (t < 336) v = wrow[320 + (t - 320)];
        else if (t == 336) v = wrow[336];
        else v = 0.f;
        Vt[(size_t)i * 352 + t] = v;
    }
    for (int t = tid; t < 36; t += 384)
        featw[i * 36 + t] = (t < 16) ? ck[t] : (t < 32) ? cm[t - 16] : (t < 35) ? ctr[t - 32] : 0.f;
}

// ============================== mask heads ================================
// One point per thread. The per-thread activation lives in 20 NAMED SCALARS
// (NOT an array): rounds 1-4 proved per-thread arrays here get either
// remat'd (VGPR=20, refetch per instance, FETCH 60MB) or scratch-homed
// (VGPR=32, 1ms). A single multi-operand asm makes A0..A19 asm-defined ->
// non-rematerializable -> allocator must keep them in VGPRs (~45 live, no
// spill at the 64-VGPR/8-wave budget). Inner loop: wave-uniform
// s_load_dwordx4 of V feeds 4 independent fma chains per point.
#define MASK_PER 8
#define MSTEP(K) { float4 w = V4[(K) * 4 + jg]; \
    h0 = fmaf(A##K, w.x, h0); h1 = fmaf(A##K, w.y, h1); \
    h2 = fmaf(A##K, w.z, h2); h3 = fmaf(A##K, w.w, h3); }
__global__ __launch_bounds__(256)
void k_mask(const float* __restrict__ maskf, const float* __restrict__ coords,
            const float* __restrict__ Vt, float* __restrict__ out,
            int N, int ostride) {
    int tid = threadIdx.x;
    int n = blockIdx.x * 256 + tid;
    bool valid = (n < N);
    int nc = valid ? n : (N - 1);
    float A0,A1,A2,A3,A4,A5,A6,A7,A8,A9,A10,A11,A12,A13,A14,A15,A16,A17,A18,A19;
    {
        const float4* fr = (const float4*)(maskf + (size_t)nc * 16);
        float4 P = fr[0], Q = fr[1], R = fr[2], S = fr[3];
        A0=P.x; A1=P.y; A2=P.z; A3=P.w;
        A4=Q.x; A5=Q.y; A6=Q.z; A7=Q.w;
        A8=R.x; A9=R.y; A10=R.z; A11=R.w;
        A12=S.x; A13=S.y; A14=S.z; A15=S.w;
        A16=coords[(size_t)nc*3]; A17=coords[(size_t)nc*3+1]; A18=coords[(size_t)nc*3+2];
        A19=1.f;
    }
    // one opaque asm: values become asm outputs -> cannot be rematerialized
    asm volatile("" : "+v"(A0), "+v"(A1), "+v"(A2), "+v"(A3), "+v"(A4),
                      "+v"(A5), "+v"(A6), "+v"(A7), "+v"(A8), "+v"(A9),
                      "+v"(A10), "+v"(A11), "+v"(A12), "+v"(A13), "+v"(A14),
                      "+v"(A15), "+v"(A16), "+v"(A17), "+v"(A18), "+v"(A19));
    int ibase = blockIdx.y * MASK_PER;
    const float4* __restrict__ V4 = (const float4*)(Vt + (size_t)ibase * 352);  // block-uniform
    float* op = out + (size_t)ibase * ostride + n;
    for (int ii = 0; ii < MASK_PER; ii++) {
        float acc = V4[84].x;               // V[336] = b2
#pragma unroll
        for (int jg = 0; jg < 4; jg++) {
            float h0 = 0.f, h1 = 0.f, h2 = 0.f, h3 = 0.f;
            MSTEP(0) MSTEP(1) MSTEP(2) MSTEP(3) MSTEP(4)
            MSTEP(5) MSTEP(6) MSTEP(7) MSTEP(8) MSTEP(9)
            MSTEP(10) MSTEP(11) MSTEP(12) MSTEP(13) MSTEP(14)
            MSTEP(15) MSTEP(16) MSTEP(17) MSTEP(18) MSTEP(19)
            float4 w2 = V4[80 + jg];        // V[320 + jg*4 .. +3]
            acc = fmaf(fmaxf(h0, 0.f), w2.x, acc);
            acc = fmaf(fmaxf(h1, 0.f), w2.y, acc);
            acc = fmaf(fmaxf(h2, 0.f), w2.z, acc);
            acc = fmaf(fmaxf(h3, 0.f), w2.w, acc);
        }
        if (valid) *op = 1.f / (1.f + __expf(-acc));
        V4 += 88;                            // 352/4
        op += ostride;
    }
}

// ============================== merge tower ===============================
// BN stats: NO global atomics. Each block writes its partial (sum,sumsq)
// row [70 doubles] to pout[blk*70 + j]; consumer reduces 64 rows at head
// with 4 independent accumulators (fully unrolled -> loads pipeline).
__global__ __launch_bounds__(256)
void k_merge1(const float* __restrict__ featw, const float* __restrict__ Wg,
              float* __restrict__ Z, double* __restrict__ pout) {
    __shared__ float F[128 * 36];
    __shared__ double redm[280];
    int tid = threadIdx.x;
    for (int t = tid; t < 128 * 36; t += 256) F[t] = featw[t];
    __syncthreads();
    int id = blockIdx.x * 256 + tid;
    int a = id >> 7, b = id & 127;
    float d[35];
#pragma unroll
    for (int k = 0; k < 35; k++) d[k] = fmaxf(fabsf(F[a * 36 + k] - F[b * 36 + k]), 1e-6f);
    float z[35];
#pragma unroll
    for (int j = 0; j < 35; j++) z[j] = 0.f;
    for (int k = 0; k < 35; k++) {
        float dk = d[k];
        const float* wr = Wg + k * 35;
#pragma unroll
        for (int j = 0; j < 35; j++) z[j] += dk * wr[j];
    }
    int wv = tid >> 6;
#pragma unroll
    for (int j = 0; j < 35; j++) {
        float s = z[j], q = z[j] * z[j];
#pragma unroll
        for (int off = 32; off > 0; off >>= 1) { s += __shfl_down(s, off); q += __shfl_down(q, off); }
        if ((tid & 63) == 0) { redm[wv * 70 + j] = (double)s; redm[wv * 70 + 35 + j] = (double)q; }
    }
    __syncthreads();
    if (tid < 70) {
        double t = redm[tid] + redm[70 + tid] + redm[140 + tid] + redm[210 + tid];
        pout[(size_t)blockIdx.x * 70 + tid] = t;
    }
    float* zr = Z + (size_t)id * 36;
#pragma unroll
    for (int j = 0; j < 35; j++) zr[j] = z[j];
}

__global__ __launch_bounds__(256)
void k_merge_mid(const float* __restrict__ Zin, const float* __restrict__ Wg,
                 float* __restrict__ Zout, const double* __restrict__ pin,
                 double* __restrict__ pout) {
    __shared__ float nrm[70];
    __shared__ double sred[70];
    __shared__ double redm[280];
    int tid = threadIdx.x;
    if (tid < 70) {
        double a0 = 0.0, a1 = 0.0, a2 = 0.0, a3 = 0.0;
#pragma unroll
        for (int b = 0; b < 64; b += 4) {
            a0 += pin[(size_t)b * 70 + tid];
            a1 += pin[(size_t)(b + 1) * 70 + tid];
            a2 += pin[(size_t)(b + 2) * 70 + tid];
            a3 += pin[(size_t)(b + 3) * 70 + tid];
        }
        sred[tid] = (a0 + a1) + (a2 + a3);
    }
    __syncthreads();
    if (tid < 35) {
        double m = sred[tid] * (1.0 / 16384.0);
        double v = sred[35 + tid] * (1.0 / 16384.0) - m * m;
        nrm[tid] = (float)m; nrm[35 + tid] = (float)rsqrt(v + (double)EPSB);
    }
    __syncthreads();
    int id = blockIdx.x * 256 + tid;
    const float* zi = Zin + (size_t)id * 36;
    float x[35];
#pragma unroll
    for (int k = 0; k < 35; k++) x[k] = fmaxf((zi[k] - nrm[k]) * nrm[35 + k], 0.f);
    float z[35];
#pragma unroll
    for (int j = 0; j < 35; j++) z[j] = 0.f;
    for (int k = 0; k < 35; k++) {
        float dk = x[k];
        const float* wr = Wg + k * 35;
#pragma unroll
        for (int j = 0; j < 35; j++) z[j] += dk * wr[j];
    }
    int wv = tid >> 6;
#pragma unroll
    for (int j = 0; j < 35; j++) {
        float s = z[j], q = z[j] * z[j];
#pragma unroll
        for (int off = 32; off > 0; off >>= 1) { s += __shfl_down(s, off); q += __shfl_down(q, off); }
        if ((tid & 63) == 0) { redm[wv * 70 + j] = (double)s; redm[wv * 70 + 35 + j] = (double)q; }
    }
    __syncthreads();
    if (tid < 70) {
        double t = redm[tid] + redm[70 + tid] + redm[140 + tid] + redm[210 + tid];
        pout[(size_t)blockIdx.x * 70 + tid] = t;
    }
    float* zr = Zout + (size_t)id * 36;
#pragma unroll
    for (int j = 0; j < 35; j++) zr[j] = z[j];
}

__global__ __launch_bounds__(256)
void k_merge_out(const float* __restrict__ Zin, const float* __restrict__ Wout,
                 const float* __restrict__ bout, const double* __restrict__ pin,
                 const int* __restrict__ cand_batch, float* __restrict__ out,
                 int N, int ostride) {
    __shared__ float nrm[70];
    __shared__ double sred[70];
    __shared__ int cb[128];
    int tid = threadIdx.x;
    if (tid < 70) {
        double a0 = 0.0, a1 = 0.0, a2 = 0.0, a3 = 0.0;
#pragma unroll
        for (int b = 0; b < 64; b += 4) {
            a0 += pin[(size_t)b * 70 + tid];
            a1 += pin[(size_t)(b + 1) * 70 + tid];
            a2 += pin[(size_t)(b + 2) * 70 + tid];
            a3 += pin[(size_t)(b + 3) * 70 + tid];
        }
        sred[tid] = (a0 + a1) + (a2 + a3);
    }
    if (tid >= 128 && tid < 256) cb[tid - 128] = cand_batch[tid - 128];
    __syncthreads();
    if (tid < 35) {
        double m = sred[tid] * (1.0 / 16384.0);
        double v = sred[35 + tid] * (1.0 / 16384.0) - m * m;
        nrm[tid] = (float)m; nrm[35 + tid] = (float)rsqrt(v + (double)EPSB);
    }
    __syncthreads();
    int id = blockIdx.x * 256 + tid;
    int a = id >> 7, b = id & 127;
    const float* zi = Zin + (size_t)id * 36;
    float s = bout[0];
    for (int k = 0; k < 35; k++)
        s += fmaxf((zi[k] - nrm[k]) * nrm[35 + k], 0.f) * Wout[k];
    float v = 1.f / (1.f + __expf(-s));
    if (cb[a] != cb[b]) v = 0.f;
    out[(size_t)a * ostride + N + b] = v;
}

// =============================== launcher =================================
extern "C" void kernel_launch(void* const* d_in, const int* in_sizes, int n_in,
                              void* d_out, int out_size, void* d_ws, size_t ws_size,
                              hipStream_t stream) {
    const float* of     = (const float*)d_in[0];
    const float* coords = (const float*)d_in[1];
    const float* heat   = (const float*)d_in[2];
    const int*   bidx   = (const int*)d_in[3];
    const float* Wm     = (const float*)d_in[4];
    const float* Wm_out = (const float*)d_in[5];
    const float* bm_out = (const float*)d_in[6];
    const float* Wk     = (const float*)d_in[7];
    const float* Wk_out = (const float*)d_in[8];
    const float* bk_out = (const float*)d_in[9];
    const float* Wg     = (const float*)d_in[10];
    const float* Wg_out = (const float*)d_in[11];
    const float* bg_out = (const float*)d_in[12];
    const float* Wwg    = (const float*)d_in[13];
    const float* bwg    = (const float*)d_in[14];
    float* out = (float*)d_out;
    float* ws  = (float*)d_ws;

    int N = in_sizes[0] / 32;          // 100000
    int ostride = N + 128;             // 100128

    float*  maskf = ws + OFF_MASKF;
    float*  kernf = ws + OFF_KERNF;
    float*  Vt    = ws + OFF_VT;
    float*  featw = ws + OFF_FEATW;
    float*  mz1   = ws + OFF_MZ1;
    float*  mz2   = ws + OFF_MZ2;
    int*    topk  = (int*)(ws + OFF_INT);
    int*    cand_batch = topk + 128;

    // tower BN partials ping-pong in mz1 region (dead until k_merge1):
    double* TPA = (double*)(ws + OFF_MZ1);
    double* TPB = (double*)(ws + OFF_MZ1 + 131072);
    // merge BN partials in kernf region (dead after k_prep):
    double* P1 = (double*)(ws + OFF_KERNF);
    double* P2 = (double*)(ws + OFF_KERNF + 16384);
    double* P3 = (double*)(ws + OFF_KERNF + 32768);

    // tower ping-pong buffers live inside d_out (overwritten before epilogue)
    float* bufAm = out;
    float* bufBm = out + (size_t)N * 32;
    float* bufAk = out + (size_t)N * 64;
    float* bufBk = out + (size_t)N * 96;

    dim3 tg2((N + 255) / 256, 2);

    k_nms<<<4, 1024, 0, stream>>>(heat, coords, bidx, N, topk);
    // both towers per launch (blockIdx.y selects); stats partials ping-pong TPA/TPB
    k_tower2<32><<<tg2, 256, 0, stream>>>(of,    of,    Wm,        Wk,        nullptr, nullptr, bufAm, bufAk, nullptr, TPA,     N);
    k_tower2<32><<<tg2, 256, 0, stream>>>(bufAm, bufAk, Wm + 1024, Wk + 1024, nullptr, nullptr, bufBm, bufBk, TPA,     TPB,     N);
    k_tower2<32><<<tg2, 256, 0, stream>>>(bufBm, bufBk, Wm + 2048, Wk + 2048, nullptr, nullptr, bufAm, bufAk, TPB,     TPA,     N);
    k_tower2<16><<<tg2, 256, 0, stream>>>(bufAm, bufAk, Wm_out,    Wk_out,    bm_out,  bk_out,  maskf, kernf, TPA,     nullptr, N);

    k_prep<<<128, 384, 0, stream>>>(topk, coords, bidx, maskf, kernf, Wwg, bwg,
                                    Vt, featw, cand_batch);
    k_mask<<<dim3((N + 255) / 256, 16), 256, 0, stream>>>(maskf, coords, Vt, out, N, ostride);

    k_merge1<<<64, 256, 0, stream>>>(featw, Wg, mz1, P1);
    k_merge_mid<<<64, 256, 0, stream>>>(mz1, Wg + 1225, mz2, P1, P2);
    k_merge_mid<<<64, 256, 0, stream>>>(mz2, Wg + 2450, mz1, P2, P3);
    k_merge_out<<<64, 256, 0, stream>>>(mz1, Wg_out, bg_out, P3, cand_batch,
                                        out, N, ostride);
}